// Round 1
// baseline (6306.987 us; speedup 1.0000x reference)
//
#include <hip/hip_runtime.h>
#include <hip/hip_bf16.h>

#define K_DIM 768
#define H_HEADS 8
#define L_BLOCKS 2
#define V_VOCAB 32000
#define B_BATCH 2
#define T_SEQ 1024
#define M_ROWS (B_BATCH*T_SEQ)   // 2048
#define KH (K_DIM*H_HEADS)       // 6144
#define FF (4*K_DIM)             // 3072
#define EPSLN 1e-5f

// ---------------- block reductions (blockDim == 256) ----------------
__device__ inline float block_reduce_sum(float v) {
  __shared__ float sm[4];
  #pragma unroll
  for (int off = 32; off > 0; off >>= 1) v += __shfl_down(v, off);
  __syncthreads();
  if ((threadIdx.x & 63) == 0) sm[threadIdx.x >> 6] = v;
  __syncthreads();
  return sm[0] + sm[1] + sm[2] + sm[3];
}
__device__ inline float block_reduce_max(float v) {
  __shared__ float sm[4];
  #pragma unroll
  for (int off = 32; off > 0; off >>= 1) v = fmaxf(v, __shfl_down(v, off));
  __syncthreads();
  if ((threadIdx.x & 63) == 0) sm[threadIdx.x >> 6] = v;
  __syncthreads();
  return fmaxf(fmaxf(sm[0], sm[1]), fmaxf(sm[2], sm[3]));
}

// ---------------- embed + positional encoding ----------------
__global__ __launch_bounds__(256)
void embed_pos_kernel(const int* __restrict__ x,
                      const float* __restrict__ embed,
                      float* __restrict__ xe) {
  int row = blockIdx.x;            // b*T + t
  int t = row & (T_SEQ - 1);
  int tok = x[row];
  const float* e = embed + (long)tok * K_DIM;
  float* o = xe + (long)row * K_DIM;
  for (int k = threadIdx.x; k < K_DIM; k += 256) {
    int i = k >> 1;                               // pair index 0..383
    float div = powf(10000.0f, (float)i / 192.0f); // 10000^(2*(2i)/768)
    float ang = (float)t / div;
    float pe = (k & 1) ? cosf(ang) : sinf(ang);
    o[k] = e[k] + pe;
  }
}

// ---------------- generic tiled f32 GEMM ----------------
// C[m,n] = act(alpha * sum_k A[m,k]*B(k,n) + bias[n])
// flags bit0: B transposed (B[n,k]); bit1: exact GELU epilogue
// batch z offset: ptr += z*Z + (z>>3)*Z8   (encodes b=z>>3, h=z&7 layouts)
#define TS 64
#define KC 16
#define LDP 68   // padded LDS row stride: 272B, 16B-aligned rows, conflict-free

__global__ __launch_bounds__(256)
void gemm_kernel(const float* __restrict__ A, const float* __restrict__ B,
                 float* __restrict__ C,
                 int Kd, int lda, int ldb, int ldc,
                 long aZ, long aZ8, long bZ, long bZ8, long cZ, long cZ8,
                 const float* __restrict__ bias, float alpha, int flags) {
  int z = blockIdx.z;
  A += (long)z * aZ + (long)(z >> 3) * aZ8;
  B += (long)z * bZ + (long)(z >> 3) * bZ8;
  C += (long)z * cZ + (long)(z >> 3) * cZ8;
  int n0 = blockIdx.x * TS;
  int m0 = blockIdx.y * TS;
  __shared__ __align__(16) float As[KC][LDP];
  __shared__ __align__(16) float Bs[KC][LDP];
  int tid = threadIdx.x;
  int tx = tid & 15, ty = tid >> 4;
  int a_c = tid & 15, a_r = tid >> 4;   // load indexing
  float acc[4][4] = {};
  for (int k0 = 0; k0 < Kd; k0 += KC) {
    #pragma unroll
    for (int i = 0; i < 4; i++) {
      int r = a_r + 16 * i;
      As[a_c][r] = A[(long)(m0 + r) * lda + (k0 + a_c)];
    }
    if (!(flags & 1)) {
      #pragma unroll
      for (int i = 0; i < 4; i++) {
        int idx = tid + 256 * i;
        int j = idx & 63, c = idx >> 6;
        Bs[c][j] = B[(long)(k0 + c) * ldb + (n0 + j)];
      }
    } else {
      #pragma unroll
      for (int i = 0; i < 4; i++) {
        int r = a_r + 16 * i;
        Bs[a_c][r] = B[(long)(n0 + r) * ldb + (k0 + a_c)];
      }
    }
    __syncthreads();
    #pragma unroll
    for (int kk = 0; kk < KC; kk++) {
      const float4 av = *(const float4*)&As[kk][ty * 4];
      const float4 bv = *(const float4*)&Bs[kk][tx * 4];
      float a[4] = {av.x, av.y, av.z, av.w};
      float b[4] = {bv.x, bv.y, bv.z, bv.w};
      #pragma unroll
      for (int i = 0; i < 4; i++)
        #pragma unroll
        for (int j = 0; j < 4; j++)
          acc[i][j] = fmaf(a[i], b[j], acc[i][j]);
    }
    __syncthreads();
  }
  #pragma unroll
  for (int i = 0; i < 4; i++) {
    int m = m0 + ty * 4 + i;
    float4 o;
    float* op = &o.x;
    #pragma unroll
    for (int j = 0; j < 4; j++) {
      int n = n0 + tx * 4 + j;
      float v = acc[i][j] * alpha;
      if (bias) v += bias[n];
      if (flags & 2) v = 0.5f * v * (1.0f + erff(v * 0.70710678118654752f));
      op[j] = v;
    }
    *(float4*)&C[(long)m * ldc + (n0 + tx * 4)] = o;
  }
}

// ---------------- row softmax over T_SEQ ----------------
__global__ __launch_bounds__(256)
void softmax_kernel(float* __restrict__ S) {
  long row = blockIdx.x;
  float* p = S + row * (long)T_SEQ;
  int tid = threadIdx.x;
  float4 v = *(float4*)&p[tid * 4];
  float m = fmaxf(fmaxf(v.x, v.y), fmaxf(v.z, v.w));
  m = block_reduce_max(m);
  v.x = __expf(v.x - m); v.y = __expf(v.y - m);
  v.z = __expf(v.z - m); v.w = __expf(v.w - m);
  float s = block_reduce_sum(v.x + v.y + v.z + v.w);
  float inv = 1.0f / s;
  v.x *= inv; v.y *= inv; v.z *= inv; v.w *= inv;
  *(float4*)&p[tid * 4] = v;
}

// ---------------- layernorm over K_DIM (in-place safe) ----------------
__global__ __launch_bounds__(256)
void layernorm_kernel(const float* __restrict__ X, float* __restrict__ Y,
                      const float* __restrict__ g, const float* __restrict__ b) {
  int row = blockIdx.x;
  const float* xp = X + (long)row * K_DIM;
  float* yp = Y + (long)row * K_DIM;
  int tid = threadIdx.x;
  float v0 = xp[tid], v1 = xp[tid + 256], v2 = xp[tid + 512];
  float mu = block_reduce_sum(v0 + v1 + v2) * (1.0f / 768.0f);
  float d0 = v0 - mu, d1 = v1 - mu, d2 = v2 - mu;
  float var = block_reduce_sum(d0 * d0 + d1 * d1 + d2 * d2) * (1.0f / 768.0f);
  float rstd = rsqrtf(var + EPSLN);
  yp[tid]       = d0 * rstd * g[tid]       + b[tid];
  yp[tid + 256] = d1 * rstd * g[tid + 256] + b[tid + 256];
  yp[tid + 512] = d2 * rstd * g[tid + 512] + b[tid + 512];
}

extern "C" void kernel_launch(void* const* d_in, const int* in_sizes, int n_in,
                              void* d_out, int out_size, void* d_ws, size_t ws_size,
                              hipStream_t stream) {
  const int*   x     = (const int*)d_in[0];
  const float* embed = (const float*)d_in[1];
  const float* Wq    = (const float*)d_in[2];
  const float* Wk    = (const float*)d_in[3];
  const float* Wv    = (const float*)d_in[4];
  const float* Wu    = (const float*)d_in[5];
  const float* bu    = (const float*)d_in[6];
  const float* ln1g  = (const float*)d_in[7];
  const float* ln1b  = (const float*)d_in[8];
  const float* Wf1   = (const float*)d_in[9];
  const float* bf1   = (const float*)d_in[10];
  const float* Wf2   = (const float*)d_in[11];
  const float* bf2   = (const float*)d_in[12];
  const float* ln2g  = (const float*)d_in[13];
  const float* ln2b  = (const float*)d_in[14];
  const float* lnfg  = (const float*)d_in[15];
  const float* lnfb  = (const float*)d_in[16];
  const float* Wout  = (const float*)d_in[17];
  const float* bout  = (const float*)d_in[18];
  float* out = (float*)d_out;

  // workspace layout (floats)
  float* ws = (float*)d_ws;
  float* xe = ws;                                  // 2048*768
  float* q  = xe + (size_t)M_ROWS * K_DIM;         // 2048*6144
  float* k_ = q  + (size_t)M_ROWS * KH;
  float* v  = k_ + (size_t)M_ROWS * KH;
  float* y  = v  + (size_t)M_ROWS * KH;
  float* s  = y  + (size_t)M_ROWS * KH;            // 16*1024*1024
  float* att = s;                                  // overlay: s dead after attention
  float* ff1 = s + (size_t)M_ROWS * K_DIM;         // still inside s region
  // total: 68,681,728 floats ≈ 275 MB

  const float scale = 0.036084391824352f;          // 1/sqrt(768)
  // strided-batch encodings: off = z*Z + (z>>3)*Z8, z = b*8+h
  const long headZ  = 768;                         // (z&7)*768 + (z>>3)*1024*6144
  const long headZ8 = 6291456 - 6144;
  const long sZ     = 1048576;                     // z * T*T

  embed_pos_kernel<<<dim3(M_ROWS), dim3(256), 0, stream>>>(x, embed, xe);

  for (int l = 0; l < L_BLOCKS; l++) {
    const float* wq  = Wq  + (size_t)l * K_DIM * KH;
    const float* wk  = Wk  + (size_t)l * K_DIM * KH;
    const float* wv  = Wv  + (size_t)l * K_DIM * KH;
    const float* wu  = Wu  + (size_t)l * KH * K_DIM;
    const float* wf1 = Wf1 + (size_t)l * K_DIM * FF;
    const float* wf2 = Wf2 + (size_t)l * FF * K_DIM;

    dim3 gQKV(KH / TS, M_ROWS / TS, 1);
    gemm_kernel<<<gQKV, 256, 0, stream>>>(xe, wq, q, K_DIM, K_DIM, KH, KH,
        0,0,0,0,0,0, nullptr, 1.0f, 0);
    gemm_kernel<<<gQKV, 256, 0, stream>>>(xe, wk, k_, K_DIM, K_DIM, KH, KH,
        0,0,0,0,0,0, nullptr, 1.0f, 0);
    gemm_kernel<<<gQKV, 256, 0, stream>>>(xe, wv, v, K_DIM, K_DIM, KH, KH,
        0,0,0,0,0,0, nullptr, 1.0f, 0);

    // S = scale * Q @ K^T   (batched over 16 (b,h))
    gemm_kernel<<<dim3(T_SEQ / TS, T_SEQ / TS, 16), 256, 0, stream>>>(
        q, k_, s, K_DIM, KH, KH, T_SEQ,
        headZ, headZ8, headZ, headZ8, sZ, 0, nullptr, scale, 1);

    softmax_kernel<<<dim3(16 * T_SEQ), dim3(256), 0, stream>>>(s);

    // Y = P @ V
    gemm_kernel<<<dim3(K_DIM / TS, T_SEQ / TS, 16), 256, 0, stream>>>(
        s, v, y, T_SEQ, T_SEQ, KH, KH,
        sZ, 0, headZ, headZ8, headZ, headZ8, nullptr, 1.0f, 0);

    // att = Y @ Wu + bu ; ln1
    gemm_kernel<<<dim3(K_DIM / TS, M_ROWS / TS, 1), 256, 0, stream>>>(
        y, wu, att, KH, KH, K_DIM, K_DIM,
        0,0,0,0,0,0, bu + l * K_DIM, 1.0f, 0);
    layernorm_kernel<<<dim3(M_ROWS), dim3(256), 0, stream>>>(
        att, att, ln1g + l * K_DIM, ln1b + l * K_DIM);

    // ff1 = gelu(att @ Wf1 + bf1)
    gemm_kernel<<<dim3(FF / TS, M_ROWS / TS, 1), 256, 0, stream>>>(
        att, wf1, ff1, K_DIM, K_DIM, FF, FF,
        0,0,0,0,0,0, bf1 + l * FF, 1.0f, 2);
    // ff2 = ff1 @ Wf2 + bf2  (into att buffer), then ln2 -> xe
    gemm_kernel<<<dim3(K_DIM / TS, M_ROWS / TS, 1), 256, 0, stream>>>(
        ff1, wf2, att, FF, FF, K_DIM, K_DIM,
        0,0,0,0,0,0, bf2 + l * K_DIM, 1.0f, 0);
    layernorm_kernel<<<dim3(M_ROWS), dim3(256), 0, stream>>>(
        att, xe, ln2g + l * K_DIM, ln2b + l * K_DIM);
  }

  layernorm_kernel<<<dim3(M_ROWS), dim3(256), 0, stream>>>(xe, xe, lnfg, lnfb);

  gemm_kernel<<<dim3(V_VOCAB / TS, M_ROWS / TS, 1), 256, 0, stream>>>(
      xe, Wout, out, K_DIM, K_DIM, V_VOCAB, V_VOCAB,
      0,0,0,0,0,0, bout, 1.0f, 0);
}

// Round 2
// 1697.838 us; speedup vs baseline: 3.7147x; 3.7147x over previous
//
#include <hip/hip_runtime.h>
#include <stdint.h>

#define K_DIM 768
#define KH    6144
#define FF_D  3072
#define V_VOCAB 32000
#define T_SEQ 1024
#define M_ROWS 2048
#define EPSLN 1e-5f

typedef __attribute__((ext_vector_type(8))) short short8;   // 8 bf16 (4 VGPRs)
typedef __attribute__((ext_vector_type(4))) float f32x4;

__device__ inline ushort f2bf(float f) {
  union { float f; uint32_t u; } v; v.f = f;
  uint32_t r = v.u + 0x7FFFu + ((v.u >> 16) & 1u);   // RNE
  return (ushort)(r >> 16);
}

__device__ inline void load_lds16(const ushort* g, char* lds) {
  __builtin_amdgcn_global_load_lds((const __attribute__((address_space(1))) void*)g,
                                   (__attribute__((address_space(3))) void*)lds,
                                   16, 0, 0);
}

// ---------------- block reductions (blockDim == 256) ----------------
__device__ inline float block_reduce_sum(float v) {
  __shared__ float sm[4];
  #pragma unroll
  for (int off = 32; off > 0; off >>= 1) v += __shfl_down(v, off);
  __syncthreads();
  if ((threadIdx.x & 63) == 0) sm[threadIdx.x >> 6] = v;
  __syncthreads();
  return sm[0] + sm[1] + sm[2] + sm[3];
}
__device__ inline float block_reduce_max(float v) {
  __shared__ float sm[4];
  #pragma unroll
  for (int off = 32; off > 0; off >>= 1) v = fmaxf(v, __shfl_down(v, off));
  __syncthreads();
  if ((threadIdx.x & 63) == 0) sm[threadIdx.x >> 6] = v;
  __syncthreads();
  return fmaxf(fmaxf(sm[0], sm[1]), fmaxf(sm[2], sm[3]));
}

// ---------------- embed + positional encoding -> bf16 ----------------
__global__ __launch_bounds__(256)
void embed_pos_kernel(const int* __restrict__ x, const float* __restrict__ embed,
                      ushort* __restrict__ xe) {
  int row = blockIdx.x;
  int t = row & (T_SEQ - 1);
  int tok = x[row];
  const float* e = embed + (long)tok * K_DIM;
  ushort* o = xe + (long)row * K_DIM;
  for (int k = threadIdx.x; k < K_DIM; k += 256) {
    int i = k >> 1;
    float div = powf(10000.0f, (float)i / 192.0f);
    float ang = (float)t / div;
    float pe = (k & 1) ? cosf(ang) : sinf(ang);
    o[k] = f2bf(e[k] + pe);
  }
}

// ---------------- transpose+convert f32 [R][C] -> bf16 [C][R] ----------------
__global__ __launch_bounds__(256)
void transpose_f2b(const float* __restrict__ in, ushort* __restrict__ out,
                   int R, int C) {
  __shared__ ushort tile[64][65];
  int r0 = blockIdx.y << 6, c0 = blockIdx.x << 6;
  int tr = threadIdx.x >> 4, tc4 = (threadIdx.x & 15) << 2;
  #pragma unroll
  for (int i = 0; i < 4; i++) {
    int row = tr + (i << 4);
    float4 v = *(const float4*)&in[(size_t)(r0 + row) * C + c0 + tc4];
    tile[row][tc4 + 0] = f2bf(v.x); tile[row][tc4 + 1] = f2bf(v.y);
    tile[row][tc4 + 2] = f2bf(v.z); tile[row][tc4 + 3] = f2bf(v.w);
  }
  __syncthreads();
  #pragma unroll
  for (int i = 0; i < 4; i++) {
    int orow = tr + (i << 4);
    ushort4 w;
    w.x = tile[tc4 + 0][orow]; w.y = tile[tc4 + 1][orow];
    w.z = tile[tc4 + 2][orow]; w.w = tile[tc4 + 3][orow];
    *(ushort4*)&out[(size_t)(c0 + orow) * R + r0 + tc4] = w;
  }
}

// ---- per-(b,h) transpose of V: bf16 [2048][6144] -> Vt [16][768][1024] ----
__global__ __launch_bounds__(256)
void transpose_v(const ushort* __restrict__ V, ushort* __restrict__ Vt) {
  int z = blockIdx.z;                              // b*8+h
  const ushort* in = V + (size_t)(z >> 3) * T_SEQ * KH + (size_t)(z & 7) * K_DIM;
  ushort* out = Vt + (size_t)z * K_DIM * T_SEQ;
  int s0 = blockIdx.y << 6, d0 = blockIdx.x << 6;
  __shared__ ushort tile[64][68];
  int tr = threadIdx.x >> 4, tc4 = (threadIdx.x & 15) << 2;
  #pragma unroll
  for (int i = 0; i < 4; i++) {
    int row = tr + (i << 4);
    ushort4 v = *(const ushort4*)&in[(size_t)(s0 + row) * KH + d0 + tc4];
    tile[row][tc4 + 0] = v.x; tile[row][tc4 + 1] = v.y;
    tile[row][tc4 + 2] = v.z; tile[row][tc4 + 3] = v.w;
  }
  __syncthreads();
  #pragma unroll
  for (int i = 0; i < 4; i++) {
    int orow = tr + (i << 4);
    ushort4 w;
    w.x = tile[tc4 + 0][orow]; w.y = tile[tc4 + 1][orow];
    w.z = tile[tc4 + 2][orow]; w.w = tile[tc4 + 3][orow];
    *(ushort4*)&out[(size_t)(d0 + orow) * T_SEQ + s0 + tc4] = w;
  }
}

// ---------------- MFMA bf16 GEMM, NT: C[m][n] = sum_k A[m][k]*B[n][k] ----------------
// 128x128 tile, BK=32, 4 waves each computing a 64x64 quadrant (4x4 MFMA tiles).
// batch offset: ptr += z*Z + (z>>3)*Z8 (elements of the respective type)
template<int OUTBF, int GELU_, int BIAS_>
__global__ __launch_bounds__(256)
void gemm_bf16(const ushort* __restrict__ A, const ushort* __restrict__ B,
               void* __restrict__ Cv, int Kd, int lda, int ldb, int ldc,
               long aZ, long aZ8, long bZ, long bZ8, long cZ, long cZ8,
               const float* __restrict__ bias, float alpha) {
  int z = blockIdx.z;
  A += (long)z * aZ + (long)(z >> 3) * aZ8;
  B += (long)z * bZ + (long)(z >> 3) * bZ8;
  long coff = (long)z * cZ + (long)(z >> 3) * cZ8;
  int m0 = blockIdx.y << 7, n0 = blockIdx.x << 7;

  __shared__ ushort As[128][32];   // [m][k], rows 64B
  __shared__ ushort Bs[128][32];   // [n][k]

  int tid = threadIdx.x;
  int wave = tid >> 6, lane = tid & 63;
  int wr = wave >> 1, wc = wave & 1;
  int m15 = lane & 15, quad = lane >> 4;

  // staging: per wave, 16 rows per issue; lane L -> row base+ (L>>2), chunk L&3
  const ushort* a_st = A + (size_t)(m0 + (wave << 4) + (lane >> 2)) * lda + ((lane & 3) << 3);
  const ushort* b_st = B + (size_t)(n0 + (wave << 4) + (lane >> 2)) * ldb + ((lane & 3) << 3);
  char* ldsA = (char*)&As[wave << 4][0];
  char* ldsB = (char*)&Bs[wave << 4][0];

  const ushort* ap = &As[(wr << 6) + m15][quad << 3];
  const ushort* bp = &Bs[(wc << 6) + m15][quad << 3];

  f32x4 acc[4][4] = {};

  for (int k0 = 0; k0 < Kd; k0 += 32) {
    load_lds16(a_st + k0, ldsA);
    load_lds16(a_st + (size_t)64 * lda + k0, ldsA + 4096);
    load_lds16(b_st + k0, ldsB);
    load_lds16(b_st + (size_t)64 * ldb + k0, ldsB + 4096);
    __syncthreads();                       // drains vmcnt before barrier
    short8 af[4], bf[4];
    #pragma unroll
    for (int i = 0; i < 4; i++) af[i] = *(const short8*)(ap + i * 512);
    #pragma unroll
    for (int j = 0; j < 4; j++) bf[j] = *(const short8*)(bp + j * 512);
    #pragma unroll
    for (int i = 0; i < 4; i++)
      #pragma unroll
      for (int j = 0; j < 4; j++)
        acc[i][j] = __builtin_amdgcn_mfma_f32_16x16x32_bf16(af[i], bf[j], acc[i][j], 0, 0, 0);
    __syncthreads();                       // compute done before next stage
  }

  // epilogue: C/D layout col=lane&15, row=quad*4+reg
  float*  Cf = (float*)Cv + coff;
  ushort* Cb = (ushort*)Cv + coff;
  int rb = m0 + (wr << 6) + (quad << 2);
  int cb = n0 + (wc << 6) + m15;
  #pragma unroll
  for (int i = 0; i < 4; i++) {
    #pragma unroll
    for (int r = 0; r < 4; r++) {
      long row = rb + i * 16 + r;
      #pragma unroll
      for (int j = 0; j < 4; j++) {
        int c = cb + j * 16;
        float v = acc[i][j][r] * alpha;
        if (BIAS_) v += bias[c];
        if (GELU_) v = 0.5f * v * (1.0f + erff(v * 0.70710678118654752f));
        if (OUTBF) Cb[row * ldc + c] = f2bf(v);
        else       Cf[row * ldc + c] = v;
      }
    }
  }
}

// ---------------- row softmax: f32 S row -> bf16 P row ----------------
__global__ __launch_bounds__(256)
void softmax_kernel(const float* __restrict__ S, ushort* __restrict__ P) {
  long row = blockIdx.x;
  const float* p = S + row * (long)T_SEQ;
  ushort* q = P + row * (long)T_SEQ;
  int tid = threadIdx.x;
  float4 v = *(const float4*)&p[tid * 4];
  float m = fmaxf(fmaxf(v.x, v.y), fmaxf(v.z, v.w));
  m = block_reduce_max(m);
  v.x = __expf(v.x - m); v.y = __expf(v.y - m);
  v.z = __expf(v.z - m); v.w = __expf(v.w - m);
  float s = block_reduce_sum(v.x + v.y + v.z + v.w);
  float inv = 1.0f / s;
  ushort4 o;
  o.x = f2bf(v.x * inv); o.y = f2bf(v.y * inv);
  o.z = f2bf(v.z * inv); o.w = f2bf(v.w * inv);
  *(ushort4*)&q[tid * 4] = o;
}

// ---------------- layernorm f32 in -> bf16 out (+ optional f32 out) ----------------
__global__ __launch_bounds__(256)
void layernorm_kernel(const float* __restrict__ X, ushort* __restrict__ Ybf,
                      float* __restrict__ Yf, const float* __restrict__ g,
                      const float* __restrict__ b) {
  int row = blockIdx.x;
  const float* xp = X + (long)row * K_DIM;
  int tid = threadIdx.x;
  float v0 = xp[tid], v1 = xp[tid + 256], v2 = xp[tid + 512];
  float mu = block_reduce_sum(v0 + v1 + v2) * (1.0f / 768.0f);
  float d0 = v0 - mu, d1 = v1 - mu, d2 = v2 - mu;
  float var = block_reduce_sum(d0 * d0 + d1 * d1 + d2 * d2) * (1.0f / 768.0f);
  float rstd = rsqrtf(var + EPSLN);
  float o0 = d0 * rstd * g[tid]       + b[tid];
  float o1 = d1 * rstd * g[tid + 256] + b[tid + 256];
  float o2 = d2 * rstd * g[tid + 512] + b[tid + 512];
  ushort* yb = Ybf + (long)row * K_DIM;
  yb[tid] = f2bf(o0); yb[tid + 256] = f2bf(o1); yb[tid + 512] = f2bf(o2);
  if (Yf) {
    float* yf = Yf + (long)row * K_DIM;
    yf[tid] = o0; yf[tid + 256] = o1; yf[tid + 512] = o2;
  }
}

extern "C" void kernel_launch(void* const* d_in, const int* in_sizes, int n_in,
                              void* d_out, int out_size, void* d_ws, size_t ws_size,
                              hipStream_t stream) {
  const int*   x     = (const int*)d_in[0];
  const float* embed = (const float*)d_in[1];
  const float* Wq    = (const float*)d_in[2];
  const float* Wk    = (const float*)d_in[3];
  const float* Wv    = (const float*)d_in[4];
  const float* Wu    = (const float*)d_in[5];
  const float* bu    = (const float*)d_in[6];
  const float* ln1g  = (const float*)d_in[7];
  const float* ln1b  = (const float*)d_in[8];
  const float* Wf1   = (const float*)d_in[9];
  const float* bf1   = (const float*)d_in[10];
  const float* Wf2   = (const float*)d_in[11];
  const float* bf2   = (const float*)d_in[12];
  const float* ln2g  = (const float*)d_in[13];
  const float* ln2b  = (const float*)d_in[14];
  const float* lnfg  = (const float*)d_in[15];
  const float* lnfb  = (const float*)d_in[16];
  const float* Wout  = (const float*)d_in[17];
  const float* bout  = (const float*)d_in[18];
  float* out = (float*)d_out;

  // ---- workspace layout (bytes), total ~265 MB ----
  char* ws = (char*)d_ws;
  size_t off = 0;
  ushort* WqT  = (ushort*)(ws + off); off += 2UL * KH * K_DIM * 2;     // [l][6144][768]
  ushort* WkT  = (ushort*)(ws + off); off += 2UL * KH * K_DIM * 2;
  ushort* WvT  = (ushort*)(ws + off); off += 2UL * KH * K_DIM * 2;
  ushort* WuT  = (ushort*)(ws + off); off += 2UL * K_DIM * KH * 2;     // [l][768][6144]
  ushort* Wf1T = (ushort*)(ws + off); off += 2UL * FF_D * K_DIM * 2;   // [l][3072][768]
  ushort* Wf2T = (ushort*)(ws + off); off += 2UL * K_DIM * FF_D * 2;   // [l][768][3072]
  ushort* xeB  = (ushort*)(ws + off); off += (size_t)M_ROWS * K_DIM * 2;
  ushort* qB   = (ushort*)(ws + off); off += (size_t)M_ROWS * KH * 2;
  ushort* kB   = (ushort*)(ws + off); off += (size_t)M_ROWS * KH * 2;
  ushort* P    = qB;                      // overlay: P (33.5MB) <= q+k (50.3MB), q/k dead post-QK^T
  ushort* vt   = (ushort*)(ws + off); off += 16UL * K_DIM * T_SEQ * 2; // [16][768][1024]
  ushort* yB   = (ushort*)(ws + off); off += (size_t)M_ROWS * KH * 2;  // also V tmp
  ushort* WoutT = vt;                     // overlay: 49.2MB <= vt+y (50.3MB), converted after loop
  float*  S    = (float*)(ws + off); off += 16UL * T_SEQ * T_SEQ * 4;
  // overlays inside the (dead-after-softmax) S region:
  float*  att  = (float*)S;                                 // 6.29 MB
  ushort* ff1  = (ushort*)((char*)S + 6291456);             // 12.58 MB
  float*  ff2  = (float*)((char*)S + 18874368);             // 6.29 MB
  ushort* attB = (ushort*)((char*)S + 25165824);            // 3.15 MB
  float*  xeF  = (float*)((char*)S + 28311552);             // 6.29 MB

  const float scale = 0.036084391824352f;  // 1/sqrt(768)
  const long hZ = 768, hZ8 = 6291456 - 6144;   // q/k/v/y per-(b,h) strides
  const long sZ = (long)T_SEQ * T_SEQ;
  const long vtZ = (long)K_DIM * T_SEQ;

  // ---- weight convert+transpose (bf16, [N][K]) ----
  for (int l = 0; l < 2; l++) {
    transpose_f2b<<<dim3(KH / 64, K_DIM / 64), 256, 0, stream>>>(
        Wq + (size_t)l * K_DIM * KH, WqT + (size_t)l * KH * K_DIM, K_DIM, KH);
    transpose_f2b<<<dim3(KH / 64, K_DIM / 64), 256, 0, stream>>>(
        Wk + (size_t)l * K_DIM * KH, WkT + (size_t)l * KH * K_DIM, K_DIM, KH);
    transpose_f2b<<<dim3(KH / 64, K_DIM / 64), 256, 0, stream>>>(
        Wv + (size_t)l * K_DIM * KH, WvT + (size_t)l * KH * K_DIM, K_DIM, KH);
    transpose_f2b<<<dim3(K_DIM / 64, KH / 64), 256, 0, stream>>>(
        Wu + (size_t)l * KH * K_DIM, WuT + (size_t)l * K_DIM * KH, KH, K_DIM);
    transpose_f2b<<<dim3(FF_D / 64, K_DIM / 64), 256, 0, stream>>>(
        Wf1 + (size_t)l * K_DIM * FF_D, Wf1T + (size_t)l * FF_D * K_DIM, K_DIM, FF_D);
    transpose_f2b<<<dim3(K_DIM / 64, FF_D / 64), 256, 0, stream>>>(
        Wf2 + (size_t)l * FF_D * K_DIM, Wf2T + (size_t)l * K_DIM * FF_D, FF_D, K_DIM);
  }

  embed_pos_kernel<<<dim3(M_ROWS), 256, 0, stream>>>(x, embed, xeB);

  for (int l = 0; l < 2; l++) {
    const ushort* wqT  = WqT  + (size_t)l * KH * K_DIM;
    const ushort* wkT  = WkT  + (size_t)l * KH * K_DIM;
    const ushort* wvT  = WvT  + (size_t)l * KH * K_DIM;
    const ushort* wuT  = WuT  + (size_t)l * K_DIM * KH;
    const ushort* wf1T = Wf1T + (size_t)l * FF_D * K_DIM;
    const ushort* wf2T = Wf2T + (size_t)l * K_DIM * FF_D;

    // QKV (V into yB as temp)
    gemm_bf16<1,0,0><<<dim3(48, 16, 1), 256, 0, stream>>>(
        xeB, wqT, qB, K_DIM, K_DIM, K_DIM, KH, 0,0,0,0,0,0, nullptr, 1.0f);
    gemm_bf16<1,0,0><<<dim3(48, 16, 1), 256, 0, stream>>>(
        xeB, wkT, kB, K_DIM, K_DIM, K_DIM, KH, 0,0,0,0,0,0, nullptr, 1.0f);
    gemm_bf16<1,0,0><<<dim3(48, 16, 1), 256, 0, stream>>>(
        xeB, wvT, yB, K_DIM, K_DIM, K_DIM, KH, 0,0,0,0,0,0, nullptr, 1.0f);
    transpose_v<<<dim3(12, 16, 16), 256, 0, stream>>>(yB, vt);

    // S = scale * Q K^T (f32)
    gemm_bf16<0,0,0><<<dim3(8, 8, 16), 256, 0, stream>>>(
        qB, kB, S, K_DIM, KH, KH, T_SEQ, hZ, hZ8, hZ, hZ8, sZ, 0, nullptr, scale);
    softmax_kernel<<<dim3(16 * T_SEQ), 256, 0, stream>>>(S, P);

    // Y = P @ V   (B = Vt[n=d][k=s])
    gemm_bf16<1,0,0><<<dim3(6, 8, 16), 256, 0, stream>>>(
        P, vt, yB, T_SEQ, T_SEQ, T_SEQ, KH, sZ, 0, vtZ, 0, hZ, hZ8, nullptr, 1.0f);

    // att = Y @ Wu + bu (f32) ; LN1 -> bf16
    gemm_bf16<0,0,1><<<dim3(6, 16, 1), 256, 0, stream>>>(
        yB, wuT, att, KH, KH, KH, K_DIM, 0,0,0,0,0,0, bu + l * K_DIM, 1.0f);
    layernorm_kernel<<<dim3(M_ROWS), 256, 0, stream>>>(
        att, attB, nullptr, ln1g + l * K_DIM, ln1b + l * K_DIM);

    // ff1 = gelu(attB @ Wf1 + bf1) bf16 ; ff2 = ff1 @ Wf2 + bf2 (f32); LN2
    gemm_bf16<1,1,1><<<dim3(24, 16, 1), 256, 0, stream>>>(
        attB, wf1T, ff1, K_DIM, K_DIM, K_DIM, FF_D, 0,0,0,0,0,0, bf1 + l * FF_D, 1.0f);
    gemm_bf16<0,0,1><<<dim3(6, 16, 1), 256, 0, stream>>>(
        ff1, wf2T, ff2, FF_D, FF_D, FF_D, K_DIM, 0,0,0,0,0,0, bf2 + l * K_DIM, 1.0f);
    layernorm_kernel<<<dim3(M_ROWS), 256, 0, stream>>>(
        ff2, xeB, xeF, ln2g + l * K_DIM, ln2b + l * K_DIM);
  }

  // final LN (f32 in from LN2), then vocab GEMM
  layernorm_kernel<<<dim3(M_ROWS), 256, 0, stream>>>(xeF, xeB, nullptr, lnfg, lnfb);
  transpose_f2b<<<dim3(V_VOCAB / 64, K_DIM / 64), 256, 0, stream>>>(Wout, WoutT, K_DIM, V_VOCAB);
  gemm_bf16<0,0,1><<<dim3(V_VOCAB / 128, 16, 1), 256, 0, stream>>>(
      xeB, WoutT, out, K_DIM, K_DIM, K_DIM, V_VOCAB, 0,0,0,0,0,0, bout, 1.0f);
}